// Round 1
// baseline (123.728 us; speedup 1.0000x reference)
//
#include <hip/hip_runtime.h>
#include <math.h>

#define BLK 256
#define MAXV 8

// ---------------------------------------------------------------------------
// Sutherland-Hodgman passes. Polygon storage: LDS planes sPX/sPY laid out as
// [vertex][tid] so that a lane's dynamic vertex index never changes its bank
// (bank = tid % 32) -> conflict-free despite per-lane divergent indices.
// Single buffer: reads are hoisted into registers (compile-time indices)
// before any append writes.  The running "last emitted vertex" is carried in
// registers between passes so prev-of-vertex-0 needs no dynamic access.
// ---------------------------------------------------------------------------

// First pass: input quad in registers, output -> LDS.
__device__ __forceinline__ void clip_first(float* __restrict__ PX, float* __restrict__ PY,
                                           int tid,
                                           const float qx[4], const float qy[4],
                                           int& n, float& lastx, float& lasty,
                                           float Ax, float Ay, float Bx, float By)
{
    float ex = Bx - Ax, ey = By - Ay;
    float s0 = ex * (qy[0] - Ay) - ey * (qx[0] - Ax);
    float s1 = ex * (qy[1] - Ay) - ey * (qx[1] - Ax);
    float s2 = ex * (qy[2] - Ay) - ey * (qx[2] - Ax);
    float s3 = ex * (qy[3] - Ay) - ey * (qx[3] - Ax);
    float vs[4] = {s0, s1, s2, s3};

    float ppx = qx[3], ppy = qy[3], ps = s3;
    int m = 0;
    float lx = ppx, ly = ppy;
#pragma unroll
    for (int i = 0; i < 4; ++i) {
        float cx = qx[i], cy = qy[i], cs = vs[i];
        bool cin = (cs >= 0.0f), pin = (ps >= 0.0f);
        if (cin != pin) {
            float den = ps - cs;
            den = (den == 0.0f) ? 1.0f : den;
            float t = __fdividef(ps, den);
            float ix = fmaf(t, cx - ppx, ppx);
            float iy = fmaf(t, cy - ppy, ppy);
            if (m < MAXV) { PX[m * BLK + tid] = ix; PY[m * BLK + tid] = iy; }
            lx = ix; ly = iy; ++m;
        }
        if (cin) {
            if (m < MAXV) { PX[m * BLK + tid] = cx; PY[m * BLK + tid] = cy; }
            lx = cx; ly = cy; ++m;
        }
        ppx = cx; ppy = cy; ps = cs;
    }
    n = (m < MAXV) ? m : MAXV;
    lastx = lx; lasty = ly;
}

// Middle pass: LDS -> LDS (reads fully buffered into registers first).
// NIN = compile-time max vertex count of the incoming polygon (+1 margin over
// the convex geometric bound, for FP-degenerate sign patterns).
template<int NIN>
__device__ __forceinline__ void clip_mid(float* __restrict__ PX, float* __restrict__ PY,
                                         int tid, int& n, float& lastx, float& lasty,
                                         float Ax, float Ay, float Bx, float By)
{
    float ex = Bx - Ax, ey = By - Ay;
    float vx[NIN], vy[NIN], vs[NIN];
#pragma unroll
    for (int i = 0; i < NIN; ++i) {
        vx[i] = PX[i * BLK + tid];
        vy[i] = PY[i * BLK + tid];
        vs[i] = ex * (vy[i] - Ay) - ey * (vx[i] - Ax);
    }
    float ppx = lastx, ppy = lasty;
    float ps = ex * (ppy - Ay) - ey * (ppx - Ax);
    int m = 0;
    float lx = lastx, ly = lasty;
#pragma unroll
    for (int i = 0; i < NIN; ++i) {
        if (i < n) {
            float cx = vx[i], cy = vy[i], cs = vs[i];
            bool cin = (cs >= 0.0f), pin = (ps >= 0.0f);
            if (cin != pin) {
                float den = ps - cs;
                den = (den == 0.0f) ? 1.0f : den;
                float t = __fdividef(ps, den);
                float ix = fmaf(t, cx - ppx, ppx);
                float iy = fmaf(t, cy - ppy, ppy);
                if (m < MAXV) { PX[m * BLK + tid] = ix; PY[m * BLK + tid] = iy; }
                lx = ix; ly = iy; ++m;
            }
            if (cin) {
                if (m < MAXV) { PX[m * BLK + tid] = cx; PY[m * BLK + tid] = cy; }
                lx = cx; ly = cy; ++m;
            }
            ppx = cx; ppy = cy; ps = cs;
        }
    }
    n = (m < MAXV) ? m : MAXV;
    lastx = lx; lasty = ly;
}

// Final pass: LDS -> shoelace area on the fly (no LDS writes).
template<int NIN>
__device__ __forceinline__ float clip_area(const float* __restrict__ PX,
                                           const float* __restrict__ PY,
                                           int tid, int n, float lastx, float lasty,
                                           float Ax, float Ay, float Bx, float By)
{
    float ex = Bx - Ax, ey = By - Ay;
    float ppx = lastx, ppy = lasty;
    float ps = ex * (ppy - Ay) - ey * (ppx - Ax);
    int m = 0;
    float fx = 0.0f, fy = 0.0f, lx = 0.0f, ly = 0.0f, area2 = 0.0f;
#pragma unroll
    for (int i = 0; i < NIN; ++i) {
        if (i < n) {
            float cx = PX[i * BLK + tid], cy = PY[i * BLK + tid];
            float cs = ex * (cy - Ay) - ey * (cx - Ax);
            bool cin = (cs >= 0.0f), pin = (ps >= 0.0f);
            if (cin != pin) {
                float den = ps - cs;
                den = (den == 0.0f) ? 1.0f : den;
                float t = __fdividef(ps, den);
                float ix = fmaf(t, cx - ppx, ppx);
                float iy = fmaf(t, cy - ppy, ppy);
                if (m == 0) { fx = ix; fy = iy; }
                else        { area2 += lx * iy - ix * ly; }
                lx = ix; ly = iy; ++m;
            }
            if (cin) {
                if (m == 0) { fx = cx; fy = cy; }
                else        { area2 += lx * cy - cx * ly; }
                lx = cx; ly = cy; ++m;
            }
            ppx = cx; ppy = cy; ps = cs;
        }
    }
    if (m > 0) area2 += lx * fy - fx * ly;
    return 0.5f * fabsf(area2);
}

__global__ __launch_bounds__(BLK)
void iou_pred_loss_kernel(const float* __restrict__ iou_preds,
                          const int*   __restrict__ one_hot,
                          const float* __restrict__ weights,
                          const float* __restrict__ anchors,
                          const float* __restrict__ box_preds,
                          const float* __restrict__ reg_targets,
                          float* __restrict__ out,
                          int N, int total)
{
    __shared__ float sPX[MAXV][BLK];
    __shared__ float sPY[MAXV][BLK];

    int tid = threadIdx.x;
    int gid = blockIdx.x * BLK + tid;
    if (gid >= total) return;

    int n_idx = gid % N;  // anchor row (anchors shared across batch)

    // ---- load anchor (only BEV-relevant components) ----
    const float* an = anchors + (size_t)n_idx * 7;
    float xa = an[0], ya = an[1], dxa = an[3], dya = an[4], ra = an[6];
    float diag = sqrtf(dxa * dxa + dya * dya);

    // ---- decode pred box (BEV components only) ----
    const float* bp = box_preds + (size_t)gid * 7;
    float x1  = fmaf(bp[0], diag, xa);
    float y1  = fmaf(bp[1], diag, ya);
    float dx1 = __expf(bp[3]) * dxa;
    float dy1 = __expf(bp[4]) * dya;
    float r1  = bp[6] + ra;

    // ---- decode target box ----
    const float* rt = reg_targets + (size_t)gid * 7;
    float x2  = fmaf(rt[0], diag, xa);
    float y2  = fmaf(rt[1], diag, ya);
    float dx2 = __expf(rt[3]) * dxa;
    float dy2 = __expf(rt[4]) * dya;
    float r2  = rt[6] + ra;

    float a1 = dx1 * dy1;
    float a2 = dx2 * dy2;

    // ---- BEV corners (CCW): local (+,+), (-,+), (-,-), (+,-) ----
    float c1 = __cosf(r1), s1 = __sinf(r1);
    float hx1 = 0.5f * dx1, hy1 = 0.5f * dy1;
    float q1x[4], q1y[4];
    q1x[0] =  hx1 * c1 - hy1 * s1 + x1;  q1y[0] =  hx1 * s1 + hy1 * c1 + y1;
    q1x[1] = -hx1 * c1 - hy1 * s1 + x1;  q1y[1] = -hx1 * s1 + hy1 * c1 + y1;
    q1x[2] = -hx1 * c1 + hy1 * s1 + x1;  q1y[2] = -hx1 * s1 - hy1 * c1 + y1;
    q1x[3] =  hx1 * c1 + hy1 * s1 + x1;  q1y[3] =  hx1 * s1 - hy1 * c1 + y1;

    float c2 = __cosf(r2), s2 = __sinf(r2);
    float hx2 = 0.5f * dx2, hy2 = 0.5f * dy2;
    float q2x[4], q2y[4];
    q2x[0] =  hx2 * c2 - hy2 * s2 + x2;  q2y[0] =  hx2 * s2 + hy2 * c2 + y2;
    q2x[1] = -hx2 * c2 - hy2 * s2 + x2;  q2y[1] = -hx2 * s2 + hy2 * c2 + y2;
    q2x[2] = -hx2 * c2 + hy2 * s2 + x2;  q2y[2] = -hx2 * s2 - hy2 * c2 + y2;
    q2x[3] =  hx2 * c2 + hy2 * s2 + x2;  q2y[3] =  hx2 * s2 - hy2 * c2 + y2;

    // ---- clip quad 1 by the 4 half-planes of quad 2 ----
    float* PX = &sPX[0][0];
    float* PY = &sPY[0][0];
    int   n;
    float lastx, lasty;
    clip_first(PX, PY, tid, q1x, q1y, n, lastx, lasty,
               q2x[0], q2y[0], q2x[1], q2y[1]);                 // n <= 5 (+FP margin)
    clip_mid<6>(PX, PY, tid, n, lastx, lasty,
                q2x[1], q2y[1], q2x[2], q2y[2]);                // n <= 6
    clip_mid<7>(PX, PY, tid, n, lastx, lasty,
                q2x[2], q2y[2], q2x[3], q2y[3]);                // n <= 7
    float inter = clip_area<8>(PX, PY, tid, n, lastx, lasty,
                               q2x[3], q2y[3], q2x[0], q2y[0]); // n <= 8

    // ---- IoU + loss ----
    float uni = a1 + a2 - inter;
    uni = fmaxf(uni, 1e-6f);
    float iou = __fdividef(inter, uni);

    float target = (one_hot[gid] > 0) ? iou : 0.0f;
    float ip = iou_preds[gid];
    float z  = __fdividef(1.0f, 1.0f + __expf(-ip));   // sigmoid
    float pt = __logf(1.0f + __expf(z)) - z * target;  // logaddexp(0,z) - z*target
    out[gid] = pt * weights[gid];
}

extern "C" void kernel_launch(void* const* d_in, const int* in_sizes, int n_in,
                              void* d_out, int out_size, void* d_ws, size_t ws_size,
                              hipStream_t stream) {
    const float* iou_preds   = (const float*)d_in[0];
    const int*   one_hot     = (const int*)  d_in[1];
    const float* weights     = (const float*)d_in[2];
    const float* anchors     = (const float*)d_in[3];
    const float* box_preds   = (const float*)d_in[4];
    const float* reg_targets = (const float*)d_in[5];
    float* out = (float*)d_out;

    int total = in_sizes[0];       // B*N
    int N     = in_sizes[3] / 7;   // anchor count

    int blocks = (total + BLK - 1) / BLK;
    iou_pred_loss_kernel<<<blocks, BLK, 0, stream>>>(
        iou_preds, one_hot, weights, anchors, box_preds, reg_targets,
        out, N, total);
}

// Round 2
// 121.551 us; speedup vs baseline: 1.0179x; 1.0179x over previous
//
#include <hip/hip_runtime.h>
#include <math.h>

#define BLK 256
#define SPARE 8   // spare LDS slot index: suppressed emissions land here

// ---------------------------------------------------------------------------
// Box1 is clipped against box2 in box2's axis-aligned local frame, so each
// half-plane sign is a single add/sub.  Edge order matches the reference's
// CCW corner order (+,+),(-,+),(-,-),(+,-):
//   pass0: y <= h2y  (s = h2y - y)
//   pass1: x >= -h2x (s = x + h2x)
//   pass2: y >= -h2y (s = y + h2y)
//   pass3: x <= h2x  (s = h2x - x)
// Scaling of s by the (positive) edge length cancels exactly in
// t = s_prev / (s_prev - s), so this matches the reference clip.
//
// Polygon storage: LDS float2 planes laid out [slot][tid] -> a lane's slot
// index never changes its bank pair; ds_read/write_b64, conflict-free.
// LDS is per-lane private scratch: NO __syncthreads needed anywhere.
// Branchless: intersection math runs unconditionally; writes that must not
// happen go to the spare slot via cndmask.  Flag logic lives in VCC (SALU).
// NaNs from non-crossing iterations (den==0 -> t=inf) are gated by selects
// before any accumulation; the den==0 guard in the reference is unreachable
// when cin!=pin (signs strictly opposite => den > 0), so it is dropped.
// Inactive iterations (i >= n) form a suffix, so garbage flowing through the
// prev-vertex chain never reaches an active iteration.
// ---------------------------------------------------------------------------

template<int MODE>
__device__ __forceinline__ float sfun(float x, float y, float K) {
    if (MODE == 0) return K - y;
    if (MODE == 1) return x + K;
    if (MODE == 2) return y + K;
    return K - x;
}

// First pass: input quad in registers -> LDS. All 4 vertices active.
template<int MODE>
__device__ __forceinline__ int clip_first(float2* __restrict__ P, int tid,
                                          const float qx[4], const float qy[4],
                                          float K)
{
    float ppx = qx[3], ppy = qy[3];
    float ps  = sfun<MODE>(ppx, ppy, K);
    bool  pin = ps >= 0.0f;
    int   m   = 0;
#pragma unroll
    for (int i = 0; i < 4; ++i) {
        float cx = qx[i], cy = qy[i];
        float cs = sfun<MODE>(cx, cy, K);
        bool  cin = cs >= 0.0f;
        bool  fi  = (cin != pin);
        float t  = __fdividef(ps, ps - cs);
        float ix = fmaf(t, cx - ppx, ppx);
        float iy = fmaf(t, cy - ppy, ppy);
        int si = fi ? m : SPARE;
        P[si * BLK + tid] = make_float2(ix, iy);
        m += fi;
        int sc = cin ? m : SPARE;
        P[sc * BLK + tid] = make_float2(cx, cy);
        m += cin;
        ppx = cx; ppy = cy; ps = cs; pin = cin;
    }
    return m;
}

// Middle pass: LDS -> LDS. Reads hoisted before any write.
template<int MODE, int NIN>
__device__ __forceinline__ int clip_mid(float2* __restrict__ P, int tid,
                                        int n, float K)
{
    float vx[NIN], vy[NIN], vs[NIN];
#pragma unroll
    for (int i = 0; i < NIN; ++i) {
        float2 v = P[i * BLK + tid];
        vx[i] = v.x; vy[i] = v.y;
        vs[i] = sfun<MODE>(v.x, v.y, K);
    }
    int pslot = n - 1; pslot = pslot < 0 ? 0 : pslot;
    float2 pv = P[pslot * BLK + tid];
    float ppx = pv.x, ppy = pv.y;
    float ps  = sfun<MODE>(ppx, ppy, K);
    bool  pin = ps >= 0.0f;
    int   m   = 0;
#pragma unroll
    for (int i = 0; i < NIN; ++i) {
        bool  act = i < n;
        float cx = vx[i], cy = vy[i], cs = vs[i];
        bool  cin = cs >= 0.0f;
        bool  fi  = act && (cin != pin);
        bool  fc  = act && cin;
        float t  = __fdividef(ps, ps - cs);
        float ix = fmaf(t, cx - ppx, ppx);
        float iy = fmaf(t, cy - ppy, ppy);
        int si = fi ? m : SPARE;
        P[si * BLK + tid] = make_float2(ix, iy);
        m += fi;
        int sc = fc ? m : SPARE;
        P[sc * BLK + tid] = make_float2(cx, cy);
        m += fc;
        ppx = cx; ppy = cy; ps = cs; pin = cin;
    }
    return m;
}

// Final pass: LDS -> shoelace area on the fly (no writes).
template<int MODE, int NIN>
__device__ __forceinline__ float clip_area(const float2* __restrict__ P, int tid,
                                           int n, float K)
{
    int pslot = n - 1; pslot = pslot < 0 ? 0 : pslot;
    float2 pv = P[pslot * BLK + tid];
    float ppx = pv.x, ppy = pv.y;
    float ps  = sfun<MODE>(ppx, ppy, K);
    bool  pin = ps >= 0.0f;
    bool  seen = false;
    float fx = 0.0f, fy = 0.0f, lx = 0.0f, ly = 0.0f, area2 = 0.0f;
#pragma unroll
    for (int i = 0; i < NIN; ++i) {
        float2 v = P[i * BLK + tid];
        float cx = v.x, cy = v.y;
        float cs = sfun<MODE>(cx, cy, K);
        bool  act = i < n;
        bool  cin = cs >= 0.0f;
        bool  fi  = act && (cin != pin);
        bool  fc  = act && cin;
        float t  = __fdividef(ps, ps - cs);
        float ix = fmaf(t, cx - ppx, ppx);
        float iy = fmaf(t, cy - ppy, ppy);
        // candidate 1: intersection point
        float c1 = fmaf(lx, iy, -(ix * ly));
        area2 += (fi && seen) ? c1 : 0.0f;
        fx = (fi && !seen) ? ix : fx;  fy = (fi && !seen) ? iy : fy;
        lx = fi ? ix : lx;             ly = fi ? iy : ly;
        seen = seen || fi;
        // candidate 2: current vertex
        float c2 = fmaf(lx, cy, -(cx * ly));
        area2 += (fc && seen) ? c2 : 0.0f;
        fx = (fc && !seen) ? cx : fx;  fy = (fc && !seen) ? cy : fy;
        lx = fc ? cx : lx;             ly = fc ? cy : ly;
        seen = seen || fc;
        ppx = cx; ppy = cy; ps = cs; pin = cin;
    }
    float wrap = fmaf(lx, fy, -(fx * ly));
    area2 += seen ? wrap : 0.0f;
    return 0.5f * fabsf(area2);
}

__global__ __launch_bounds__(BLK)
void iou_pred_loss_kernel(const float* __restrict__ iou_preds,
                          const int*   __restrict__ one_hot,
                          const float* __restrict__ weights,
                          const float* __restrict__ anchors,
                          const float* __restrict__ box_preds,
                          const float* __restrict__ reg_targets,
                          float* __restrict__ out,
                          int N)
{
    __shared__ float2 sP[(SPARE + 1) * BLK];   // 9 slots * 256 lanes * 8B = 18.4 KB

    int tid   = threadIdx.x;
    int n_idx = blockIdx.x * BLK + tid;        // anchor row
    if (n_idx >= N) return;
    int gid = blockIdx.y * N + n_idx;          // (batch, row) flat index

    // ---- anchor (BEV components) ----
    const float* an = anchors + (size_t)n_idx * 7;
    float xa = an[0], ya = an[1], dxa = an[3], dya = an[4], ra = an[6];
    float diag = sqrtf(fmaf(dxa, dxa, dya * dya));

    // ---- decode pred box ----
    const float* bp = box_preds + (size_t)gid * 7;
    float x1  = fmaf(bp[0], diag, xa);
    float y1  = fmaf(bp[1], diag, ya);
    float dx1 = __expf(bp[3]) * dxa;
    float dy1 = __expf(bp[4]) * dya;
    float r1  = bp[6] + ra;

    // ---- decode target box ----
    const float* rt = reg_targets + (size_t)gid * 7;
    float x2  = fmaf(rt[0], diag, xa);
    float y2  = fmaf(rt[1], diag, ya);
    float dx2 = __expf(rt[3]) * dxa;
    float dy2 = __expf(rt[4]) * dya;
    float r2  = rt[6] + ra;

    float a1 = dx1 * dy1;
    float a2 = dx2 * dy2;

    // ---- transform box1 corners into box2's axis-aligned frame ----
    float c2v = __cosf(r2), s2v = __sinf(r2);
    float dr  = r1 - r2;
    float cd  = __cosf(dr), sd = __sinf(dr);
    float ddx = x1 - x2, ddy = y1 - y2;
    float tx  = fmaf(c2v, ddx,  s2v * ddy);    // R(-r2) * (p1 - p2)
    float ty  = fmaf(-s2v, ddx, c2v * ddy);
    float h1x = 0.5f * dx1, h1y = 0.5f * dy1;
    float h2x = 0.5f * dx2, h2y = 0.5f * dy2;
    float e1x = h1x * cd,  e1y = h1x * sd;     // R(dr)*(h1x,0)
    float e2x = -h1y * sd, e2y = h1y * cd;     // R(dr)*(0,h1y)
    float qx[4], qy[4];
    qx[0] = tx + e1x + e2x;  qy[0] = ty + e1y + e2y;   // (+,+)
    qx[1] = tx - e1x + e2x;  qy[1] = ty - e1y + e2y;   // (-,+)
    qx[2] = tx - e1x - e2x;  qy[2] = ty - e1y - e2y;   // (-,-)
    qx[3] = tx + e1x - e2x;  qy[3] = ty + e1y - e2y;   // (+,-)

    // ---- 4 clip passes against box2's axis-aligned edges ----
    int m = clip_first<0>(sP, tid, qx, qy, h2y);       // y <= h2y
    int n = m < 6 ? m : 6;
    m = clip_mid<1, 6>(sP, tid, n, h2x);               // x >= -h2x
    n = m < 7 ? m : 7;
    m = clip_mid<2, 7>(sP, tid, n, h2y);               // y >= -h2y
    n = m < 8 ? m : 8;
    float inter = clip_area<3, 8>(sP, tid, n, h2x);    // x <= h2x

    // ---- IoU + loss ----
    float uni = a1 + a2 - inter;
    uni = fmaxf(uni, 1e-6f);
    float iou = __fdividef(inter, uni);

    float target = (one_hot[gid] > 0) ? iou : 0.0f;
    float ip = iou_preds[gid];
    float z  = __fdividef(1.0f, 1.0f + __expf(-ip));   // sigmoid
    float pt = __logf(1.0f + __expf(z)) - z * target;  // logaddexp(0,z) - z*target
    out[gid] = pt * weights[gid];
}

extern "C" void kernel_launch(void* const* d_in, const int* in_sizes, int n_in,
                              void* d_out, int out_size, void* d_ws, size_t ws_size,
                              hipStream_t stream) {
    const float* iou_preds   = (const float*)d_in[0];
    const int*   one_hot     = (const int*)  d_in[1];
    const float* weights     = (const float*)d_in[2];
    const float* anchors     = (const float*)d_in[3];
    const float* box_preds   = (const float*)d_in[4];
    const float* reg_targets = (const float*)d_in[5];
    float* out = (float*)d_out;

    int total = in_sizes[0];       // B*N
    int N     = in_sizes[3] / 7;   // anchor count
    int B     = total / N;

    dim3 grid((N + BLK - 1) / BLK, B);
    iou_pred_loss_kernel<<<grid, dim3(BLK), 0, stream>>>(
        iou_preds, one_hot, weights, anchors, box_preds, reg_targets,
        out, N);
}

// Round 3
// 115.307 us; speedup vs baseline: 1.0730x; 1.0542x over previous
//
#include <hip/hip_runtime.h>
#include <math.h>

#define BLK 256

// ---------------------------------------------------------------------------
// Rotated-box intersection area WITHOUT polygon clipping.
//
// area(P∩Q) = (1/2) ∮_{∂(P∩Q)} (x dy − y dx).  The boundary decomposes into
// (a) parts of ∂P inside Q and (b) parts of ∂Q inside P (exact for
// non-coincident boundaries; coincidence is measure-zero for random data).
// Each part is a segment: an edge Liang-Barsky-clipped to an axis-aligned
// box in the box's own local frame.
//   - P-edge pieces: P's corners expressed in Q's frame (Q = AAB, half-dims
//     h2x,h2y); Green terms accumulate directly in Q's frame.
//   - Q-edge pieces: Q's corners expressed in P's frame (P = AAB, half-dims
//     h1x,h1y); Green terms computed in P's frame.  x dy − y dx is
//     rotation-invariant, so only the translation between frames matters:
//     summed over all Q-pieces it contributes exactly
//     (1/2)·cross(t, R·ΣΔ), where p_Q = R·p_P + t and Δ = piece endpoint
//     displacement.  (Hand-verified on shifted unit squares.)
// Fully branchless: empty clips collapse to zero-length pieces whose
// contribution is exactly 0; zero direction components are clamped to
// ±1e-30 so slab tests produce huge-but-finite s values (no NaN/inf).
// No LDS, no dynamic indexing.
// ---------------------------------------------------------------------------

__device__ __forceinline__ void edge_piece(float px, float py, float ex, float ey,
                                           float hx, float hy,
                                           float& area2, float& Dx, float& Dy)
{
    // clip segment p + s*e, s in [0,1], to box [-hx,hx] x [-hy,hy]
    float gx = copysignf(fmaxf(fabsf(ex), 1e-30f), ex);
    float gy = copysignf(fmaxf(fabsf(ey), 1e-30f), ey);
    float rx = __fdividef(1.0f, gx);
    float ry = __fdividef(1.0f, gy);
    float sx0 = (-hx - px) * rx, sx1 = (hx - px) * rx;
    float sy0 = (-hy - py) * ry, sy1 = (hy - py) * ry;
    float smin = fmaxf(fmaxf(fminf(sx0, sx1), fminf(sy0, sy1)), 0.0f);
    float smax = fminf(fminf(fmaxf(sx0, sx1), fmaxf(sy0, sy1)), 1.0f);
    smax = fmaxf(smax, smin);                  // empty -> zero-length at smin
    float ax = fmaf(smin, ex, px), ay = fmaf(smin, ey, py);
    float bx = fmaf(smax, ex, px), by = fmaf(smax, ey, py);
    float ux = bx - ax, uy = by - ay;          // exactly 0 when smin==smax
    area2 += fmaf(ax, uy, -(ay * ux));         // cross(a, b-a) == cross(a,b)
    Dx += ux; Dy += uy;
}

__global__ __launch_bounds__(BLK)
void iou_pred_loss_kernel(const float* __restrict__ iou_preds,
                          const int*   __restrict__ one_hot,
                          const float* __restrict__ weights,
                          const float* __restrict__ anchors,
                          const float* __restrict__ box_preds,
                          const float* __restrict__ reg_targets,
                          float* __restrict__ out,
                          int N)
{
    int tid   = threadIdx.x;
    int n_idx = blockIdx.x * BLK + tid;        // anchor row
    if (n_idx >= N) return;
    int gid = blockIdx.y * N + n_idx;          // (batch, row) flat index

    // ---- anchor (BEV components) ----
    const float* an = anchors + (size_t)n_idx * 7;
    float xa = an[0], ya = an[1], dxa = an[3], dya = an[4], ra = an[6];
    float diag = sqrtf(fmaf(dxa, dxa, dya * dya));

    // ---- decode pred box (P) ----
    const float* bp = box_preds + (size_t)gid * 7;
    float x1  = fmaf(bp[0], diag, xa);
    float y1  = fmaf(bp[1], diag, ya);
    float dx1 = __expf(bp[3]) * dxa;
    float dy1 = __expf(bp[4]) * dya;
    float r1  = bp[6] + ra;

    // ---- decode target box (Q) ----
    const float* rt = reg_targets + (size_t)gid * 7;
    float x2  = fmaf(rt[0], diag, xa);
    float y2  = fmaf(rt[1], diag, ya);
    float dx2 = __expf(rt[3]) * dxa;
    float dy2 = __expf(rt[4]) * dya;
    float r2  = rt[6] + ra;

    float a1 = dx1 * dy1;
    float a2 = dx2 * dy2;

    float h1x = 0.5f * dx1, h1y = 0.5f * dy1;
    float h2x = 0.5f * dx2, h2y = 0.5f * dy2;

    // ---- P in Q's frame: p_Q = R(dr)·p_P + t ----
    float c2v = __cosf(r2), s2v = __sinf(r2);
    float dr  = r1 - r2;
    float cd  = __cosf(dr), sd = __sinf(dr);
    float ddx = x1 - x2, ddy = y1 - y2;
    float tx  = fmaf(c2v, ddx,  s2v * ddy);    // R(-r2)·(c1 - c2)
    float ty  = fmaf(-s2v, ddx, c2v * ddy);

    // P corners in Q frame (CCW): t ± u ± v, u = R·(h1x,0), v = R·(0,h1y)
    float ux_ = h1x * cd,  uy_ = h1x * sd;
    float vx_ = -h1y * sd, vy_ = h1y * cd;
    float pX[4], pY[4];
    pX[0] = tx + ux_ + vx_;  pY[0] = ty + uy_ + vy_;
    pX[1] = tx - ux_ + vx_;  pY[1] = ty - uy_ + vy_;
    pX[2] = tx - ux_ - vx_;  pY[2] = ty - uy_ - vy_;
    pX[3] = tx + ux_ - vx_;  pY[3] = ty + uy_ - vy_;

    // Q corners in P frame (CCW): o ± u' ± v', u' = R^T·(h2x,0),
    // v' = R^T·(0,h2y), o = -R^T·t
    float upx = h2x * cd,  upy = -h2x * sd;
    float vpx = h2y * sd,  vpy = h2y * cd;
    float ox  = -(fmaf(cd, tx,  sd * ty));
    float oy  = -(fmaf(-sd, tx, cd * ty));
    float qX[4], qY[4];
    qX[0] = ox + upx + vpx;  qY[0] = oy + upy + vpy;
    qX[1] = ox - upx + vpx;  qY[1] = oy - upy + vpy;
    qX[2] = ox - upx - vpx;  qY[2] = oy - upy - vpy;
    qX[3] = ox + upx - vpx;  qY[3] = oy + upy - vpy;

    // ---- accumulate Green terms ----
    float area2 = 0.0f;
    float dumDx = 0.0f, dumDy = 0.0f;          // P-pieces: displacement unused
#pragma unroll
    for (int i = 0; i < 4; ++i) {
        int j = (i + 1) & 3;
        edge_piece(pX[i], pY[i], pX[j] - pX[i], pY[j] - pY[i],
                   h2x, h2y, area2, dumDx, dumDy);
    }
    float Dx = 0.0f, Dy = 0.0f;                // Q-pieces: need net displacement
#pragma unroll
    for (int i = 0; i < 4; ++i) {
        int j = (i + 1) & 3;
        edge_piece(qX[i], qY[i], qX[j] - qX[i], qY[j] - qY[i],
                   h1x, h1y, area2, Dx, Dy);
    }
    // translation correction: cross(t, R·D)
    float RDx = fmaf(cd, Dx, -(sd * Dy));
    float RDy = fmaf(sd, Dx,   cd * Dy);
    area2 += fmaf(tx, RDy, -(ty * RDx));

    float inter = 0.5f * fabsf(area2);

    // ---- IoU + loss ----
    float uni = fmaxf(a1 + a2 - inter, 1e-6f);
    float iou = __fdividef(inter, uni);

    float target = (one_hot[gid] > 0) ? iou : 0.0f;
    float ip = iou_preds[gid];
    float z  = __fdividef(1.0f, 1.0f + __expf(-ip));   // sigmoid
    float pt = __logf(1.0f + __expf(z)) - z * target;  // logaddexp(0,z) - z*target
    out[gid] = pt * weights[gid];
}

extern "C" void kernel_launch(void* const* d_in, const int* in_sizes, int n_in,
                              void* d_out, int out_size, void* d_ws, size_t ws_size,
                              hipStream_t stream) {
    const float* iou_preds   = (const float*)d_in[0];
    const int*   one_hot     = (const int*)  d_in[1];
    const float* weights     = (const float*)d_in[2];
    const float* anchors     = (const float*)d_in[3];
    const float* box_preds   = (const float*)d_in[4];
    const float* reg_targets = (const float*)d_in[5];
    float* out = (float*)d_out;

    int total = in_sizes[0];       // B*N
    int N     = in_sizes[3] / 7;   // anchor count
    int B     = total / N;

    dim3 grid((N + BLK - 1) / BLK, B);
    iou_pred_loss_kernel<<<grid, dim3(BLK), 0, stream>>>(
        iou_preds, one_hot, weights, anchors, box_preds, reg_targets,
        out, N);
}